// Round 2
// 157.682 us; speedup vs baseline: 1.0008x; 1.0008x over previous
//
#include <hip/hip_runtime.h>

// BCELoss(reduce=False) + "already-correct -> 0" masking, N fp32 elements.
//   q = (y==1) ? p : 1-p;  loss = (q > 0.5) ? 0 : -max(ln q, -100)
// R4: nontemporal loads/stores broke the ~2.1 TB/s L2-write-allocate wall.
// R5: K=4 float4/thread, 128 B/lane in flight -> kernel <40 us (off top-5).
// R6: CHUNKS=2 sequential chunks per thread -> grid 2048 = exactly 8 blocks/CU
//     (32 waves/CU, ONE dispatch round instead of two). K kept at 4 per chunk
//     so live VGPRs stay ~40 (<64) and occupancy stays at the 32-wave cap.
//     Floor: 192 MiB @ ~6.4 TB/s ~ 31 us.
// R7: identical resubmit — R6 bench was an infra failure (container), no data.

typedef float vfloat4 __attribute__((ext_vector_type(4)));

#define K      4    // float4s per chunk
#define CHUNKS 2    // sequential chunks per thread
#define BLOCK  256

__device__ __forceinline__ float bce1(float p, float y) {
    float q = (y == 1.0f) ? p : (1.0f - p);
    float lg = __builtin_amdgcn_logf(q) * 0.6931471805599453f;  // v_log_f32 -> ln
    float ll = fmaxf(lg, -100.0f);   // torch clamp (inert for q >= 1e-4)
    return (q > 0.5f) ? 0.0f : -ll;
}

__device__ __forceinline__ vfloat4 bce4(vfloat4 p, vfloat4 y) {
    vfloat4 o;
    o.x = bce1(p.x, y.x);
    o.y = bce1(p.y, y.y);
    o.z = bce1(p.z, y.z);
    o.w = bce1(p.w, y.w);
    return o;
}

__global__ void __launch_bounds__(BLOCK)
bce_loss_kernel(const vfloat4* __restrict__ p4,
                const vfloat4* __restrict__ y4,
                vfloat4* __restrict__ o4,
                int n4,
                const float* __restrict__ p_s,
                const float* __restrict__ y_s,
                float* __restrict__ o_s,
                int n) {
    const int span  = BLOCK * K;                       // float4s per chunk
    int base0 = blockIdx.x * (span * CHUNKS) + threadIdx.x;
    int last  = base0 + (CHUNKS - 1) * span + BLOCK * (K - 1);

    if (last < n4) {
        // fast path: whole thread-span in range. Chunks run sequentially so
        // only 8 float4 are live at once (occupancy stays 32 waves/CU);
        // within a chunk all 2K nt loads issue before first use.
        #pragma unroll
        for (int c = 0; c < CHUNKS; ++c) {
            int base = base0 + c * span;
            vfloat4 p[K], y[K];
            #pragma unroll
            for (int k = 0; k < K; ++k)
                p[k] = __builtin_nontemporal_load(&p4[base + k * BLOCK]);
            #pragma unroll
            for (int k = 0; k < K; ++k)
                y[k] = __builtin_nontemporal_load(&y4[base + k * BLOCK]);
            #pragma unroll
            for (int k = 0; k < K; ++k)
                __builtin_nontemporal_store(bce4(p[k], y[k]), &o4[base + k * BLOCK]);
        }
    } else {
        #pragma unroll
        for (int c = 0; c < CHUNKS; ++c) {
            #pragma unroll
            for (int k = 0; k < K; ++k) {
                int i = base0 + c * span + k * BLOCK;
                if (i < n4) {
                    vfloat4 p = __builtin_nontemporal_load(&p4[i]);
                    vfloat4 y = __builtin_nontemporal_load(&y4[i]);
                    __builtin_nontemporal_store(bce4(p, y), &o4[i]);
                }
            }
        }
    }

    // scalar tail (n % 4) — empty for N = 2^24
    if (base0 == 0) {
        for (int j = n4 * 4; j < n; ++j) {
            float pj = p_s[j];
            float yj = y_s[j];
            o_s[j] = bce1(pj, yj);
        }
    }
}

extern "C" void kernel_launch(void* const* d_in, const int* in_sizes, int n_in,
                              void* d_out, int out_size, void* d_ws, size_t ws_size,
                              hipStream_t stream) {
    const float* y_pred   = (const float*)d_in[0];
    const float* y_actual = (const float*)d_in[1];
    float* out = (float*)d_out;
    int n  = in_sizes[0];
    int n4 = n >> 2;

    const int block = BLOCK;
    const int per_block = block * K * CHUNKS;      // float4s per block (2048)
    int grid = (n4 + per_block - 1) / per_block;   // 2048 for N=2^24
    bce_loss_kernel<<<grid, block, 0, stream>>>(
        (const vfloat4*)y_pred, (const vfloat4*)y_actual, (vfloat4*)out, n4,
        y_pred, y_actual, out, n);
}